// Round 5
// baseline (97.559 us; speedup 1.0000x reference)
//
#include <hip/hip_runtime.h>
#include <stdint.h>

// Y = tanh(X @ W + b):  M=65536 (8*64*128), K=512, N=512, all fp32.
// R5: single-pass for X (fp32->bf16 cvt fused into the GEMM's A-staging),
// W pre-converted once (cvtW) to a bf16 transposed swizzled tile image in ws
// so B staging is pure global_load_lds (0 VGPR). A staging = 8 float4 loads
// + pk2 cvt + 4 swizzled ds_write_b128 per K-step, NO cross-step register
// prefetch (R2/R3 lesson: that spills under the 128-VGPR/4-block cap).
// Traffic floor ~268 MB (X read once via same-XCD L2 reuse, Y write) vs
// R4's two-pass 402 MB.

typedef short bf16x8 __attribute__((ext_vector_type(8)));
typedef float f32x16 __attribute__((ext_vector_type(16)));

#define KTOT 512
#define NTOT 512
#define BK   64
#define WT_BYTES   524288ull      // 512*512*2
#define WS_NEEDED  WT_BYTES

typedef __attribute__((address_space(3))) uint8_t lds8;
typedef __attribute__((address_space(1))) const uint8_t glb8;

__device__ __forceinline__ uint32_t pk2(float a, float b) {
  uint16_t lo = __builtin_bit_cast(uint16_t, (__bf16)a);   // RNE
  uint16_t hi = __builtin_bit_cast(uint16_t, (__bf16)b);
  return (uint32_t)lo | ((uint32_t)hi << 16);
}

__device__ __forceinline__ float fast_tanh(float z) {
  float t = __builtin_amdgcn_exp2f(z * 2.8853900817779268f);
  return 1.0f - 2.0f * __builtin_amdgcn_rcpf(t + 1.0f);
}

// ------- pass 1: W fp32 [k][n] -> bf16 transposed swizzled tile image -------
// Image: 32 tiles (tn 0..3, ts 0..7) of 16KB: [n:128 rows][8 chunks of 16B],
// chunk j stored at slot j^(row&7).
__global__ __launch_bounds__(256)
void cvtW_kernel(const float* __restrict__ W, uint8_t* __restrict__ Wt) {
  const int c   = blockIdx.x * 256 + threadIdx.x;     // 0..32767
  const int j   = c & 7;
  const int r   = (c >> 3) & 127;                     // local n
  const int tsn = c >> 10;                            // tn*8+ts, 0..31
  const int ts  = tsn & 7;
  const int tn  = tsn >> 3;
  const int n   = tn * 128 + r;
  const int k0  = ts * 64 + j * 8;
  float e[8];
#pragma unroll
  for (int i = 0; i < 8; ++i) e[i] = W[(size_t)(k0 + i) * NTOT + n];
  uint4 v = make_uint4(pk2(e[0], e[1]), pk2(e[2], e[3]), pk2(e[4], e[5]), pk2(e[6], e[7]));
  *(uint4*)(Wt + ((size_t)tsn << 14) + (r << 7) + ((j ^ (r & 7)) << 4)) = v;
}

// ---------------- pass 2: fused cvt(A) + GEMM + bias + tanh ----------------
__global__ __launch_bounds__(256, 4)
void hotdd_fused(const float* __restrict__ X, const uint8_t* __restrict__ Wt,
                 const float* __restrict__ Bv, float* __restrict__ Y) {
  __shared__ uint8_t Ab[16384];   // A tile [m:128][k:64] bf16, swizzled
  __shared__ uint8_t Bb[16384];   // W tile^T [n:128][k:64] bf16, swizzled

  // XCD swizzle: the 4 bn-blocks sharing an X strip get dispatch ids
  // {d, d+8, d+16, d+24} -> same XCD, adjacent -> X re-reads hit that L2.
  const int d  = blockIdx.x;
  const int bm = ((d >> 5) << 3) | (d & 7);   // 0..511
  const int bn = (d >> 3) & 3;                // 0..3

  const int tid  = threadIdx.x;
  const int lane = tid & 63;
  const int wv   = tid >> 6;
  const int wr   = (wv >> 1) * 64;
  const int wc   = (wv & 1) * 64;
  const int lo5  = lane & 31;
  const int hi1  = lane >> 5;
  const int rs   = lo5 & 7;

  // ---- A staging map: thread -> (row am, half ah of 64 k)
  const int am   = tid >> 1;
  const int ah   = tid & 1;
  const int amz  = am & 7;
  const int abase = am * 128;
  const float* Ag = X + (size_t)(bm * 128 + am) * KTOT + ah * 32;

  // ---- B staging: wave wv copies bytes [wv*4096, wv*4096+4096) of the
  // 16KB step-tile, as 4 chunks of 1KB (64 lanes x 16B), image == LDS layout.
  const uint8_t* Bsrc = Wt + ((size_t)(bn * 8) << 14) + wv * 4096 + lane * 16;
  uint8_t* Bdst = Bb + wv * 4096;   // wave-uniform; HW adds lane*16

#define AST(J, P, Q)                                                          \
    *(uint4*)(Ab + abase + (((((ah << 2) + (J)) ^ amz)) << 4)) =              \
      make_uint4(pk2(P.x, P.y), pk2(P.z, P.w),                                \
                 pk2(Q.x, Q.y), pk2(Q.z, Q.w));

  f32x16 acc00 = {}, acc01 = {}, acc10 = {}, acc11 = {};

  const uint8_t* Ard0 = Ab + (wr + lo5) * 128;
  const uint8_t* Ard1 = Ard0 + 32 * 128;
  const uint8_t* Brd0 = Bb + (wc + lo5) * 128;
  const uint8_t* Brd1 = Brd0 + 32 * 128;

#define MFMA_PHASE() do {                                                     \
    _Pragma("unroll")                                                         \
    for (int kk = 0; kk < 4; ++kk) {                                          \
      const int sb = ((((kk << 1) | hi1) ^ rs) << 4);                         \
      bf16x8 fa0 = *(const bf16x8*)(Ard0 + sb);                               \
      bf16x8 fa1 = *(const bf16x8*)(Ard1 + sb);                               \
      bf16x8 fb0 = *(const bf16x8*)(Brd0 + sb);                               \
      bf16x8 fb1 = *(const bf16x8*)(Brd1 + sb);                               \
      acc00 = __builtin_amdgcn_mfma_f32_32x32x16_bf16(fa0, fb0, acc00, 0,0,0);\
      acc01 = __builtin_amdgcn_mfma_f32_32x32x16_bf16(fa0, fb1, acc01, 0,0,0);\
      acc10 = __builtin_amdgcn_mfma_f32_32x32x16_bf16(fa1, fb0, acc10, 0,0,0);\
      acc11 = __builtin_amdgcn_mfma_f32_32x32x16_bf16(fa1, fb1, acc11, 0,0,0);\
    }                                                                         \
  } while (0)

#pragma unroll 1
  for (int s = 0; s < 8; ++s) {
    // 1) issue B async global->LDS (no regs, flies under A's staging)
    {
      const uint8_t* bs_ = Bsrc + ((size_t)s << 14);
#pragma unroll
      for (int q = 0; q < 4; ++q)
        __builtin_amdgcn_global_load_lds((glb8*)(bs_ + q * 1024),
                                         (lds8*)(Bdst + q * 1024), 16, 0, 0);
    }
    // 2) A: load 32 fp32, cvt RNE, 4 swizzled ds_write_b128
    {
      const float* ap_ = Ag + s * BK;
      float4 a0 = ((const float4*)ap_)[0];
      float4 a1 = ((const float4*)ap_)[1];
      float4 a2 = ((const float4*)ap_)[2];
      float4 a3 = ((const float4*)ap_)[3];
      float4 a4 = ((const float4*)ap_)[4];
      float4 a5 = ((const float4*)ap_)[5];
      float4 a6 = ((const float4*)ap_)[6];
      float4 a7 = ((const float4*)ap_)[7];
      AST(0, a0, a1) AST(1, a2, a3) AST(2, a4, a5) AST(3, a6, a7)
    }
    asm volatile("s_waitcnt vmcnt(0)" ::: "memory");
    __syncthreads();                 // B landed + A writes visible
    MFMA_PHASE();
    __syncthreads();                 // reads done before next overwrite
  }

  const int gn0 = bn * 128 + wc + lo5;
  const int gn1 = gn0 + 32;
  const float bv0 = Bv[gn0];
  const float bv1 = Bv[gn1];

#define EPI(ACC, MI, GN, BVAL) do {                                           \
    _Pragma("unroll")                                                         \
    for (int r = 0; r < 16; ++r) {                                            \
      const int mloc = wr + (MI) * 32 + (hi1 << 2) + ((r >> 2) << 3) + (r & 3);\
      Y[(size_t)(bm * 128 + mloc) * NTOT + (GN)] = fast_tanh((ACC)[r] + (BVAL));\
    }                                                                         \
  } while (0)

  EPI(acc00, 0, gn0, bv0);
  EPI(acc01, 0, gn1, bv1);
  EPI(acc10, 1, gn0, bv0);
  EPI(acc11, 1, gn1, bv1);
}

// ---------------- fallback: R1 kernel (146us), used if ws too small ----------
struct Regs {
  float4 a0,a1,a2,a3,a4,a5,a6,a7;
  float4 u0,u1,u2,u3;
  float4 v0,v1,v2,v3;
};

__global__ __launch_bounds__(256, 2)
void hotdd_fallback(const float* __restrict__ X, const float* __restrict__ W,
                    const float* __restrict__ Bv, float* __restrict__ Y) {
  __shared__ char Ab[128 * BK * 2];
  __shared__ char Bb[128 * BK * 2];
  const int d  = blockIdx.x;
  const int bm = ((d >> 5) << 3) | (d & 7);
  const int bn = (d >> 3) & 3;
  const int tid  = threadIdx.x;
  const int lane = tid & 63;
  const int wv   = tid >> 6;
  const int wr   = (wv >> 1) * 64;
  const int wc   = (wv & 1) * 64;
  const int lo5  = lane & 31;
  const int hi1  = lane >> 5;
  const int rs   = lo5 & 7;
  const int am   = tid >> 1;
  const int ah   = tid & 1;
  const int amz  = am & 7;
  const int abase = am * 128;
  const float* Ag = X + (size_t)(bm * 128 + am) * KTOT + ah * 32;
  const int kp = lo5;
  const int ng = wv * 32 + hi1 * 16;
  const float* Bg = W + (size_t)(2 * kp) * NTOT + bn * 128 + ng;

#define LOADR(R, K0) do {                                                     \
    const float* ap_ = Ag + (K0);                                             \
    R.a0 = *(const float4*)(ap_ +  0); R.a1 = *(const float4*)(ap_ +  4);     \
    R.a2 = *(const float4*)(ap_ +  8); R.a3 = *(const float4*)(ap_ + 12);     \
    R.a4 = *(const float4*)(ap_ + 16); R.a5 = *(const float4*)(ap_ + 20);     \
    R.a6 = *(const float4*)(ap_ + 24); R.a7 = *(const float4*)(ap_ + 28);     \
    const float* bp_ = Bg + (size_t)(K0) * NTOT;                              \
    R.u0 = *(const float4*)(bp_ +  0); R.u1 = *(const float4*)(bp_ +  4);     \
    R.u2 = *(const float4*)(bp_ +  8); R.u3 = *(const float4*)(bp_ + 12);     \
    R.v0 = *(const float4*)(bp_ + NTOT +  0); R.v1 = *(const float4*)(bp_ + NTOT +  4); \
    R.v2 = *(const float4*)(bp_ + NTOT +  8); R.v3 = *(const float4*)(bp_ + NTOT + 12); \
  } while (0)

#define ASTF(R, J, P, Q)                                                      \
    *(uint4*)(Ab + abase + (((((ah << 2) + (J)) ^ amz)) << 4)) =              \
      make_uint4(pk2(R.P.x, R.P.y), pk2(R.P.z, R.P.w),                        \
                 pk2(R.Q.x, R.Q.y), pk2(R.Q.z, R.Q.w));
#define BSTF(R, I, UV, C)                                                     \
    *(uint32_t*)(Bb + (ng + (I)) * 128 + ((kp << 2) ^ (((I) & 7) << 4))) =    \
      pk2(R.u##UV.C, R.v##UV.C);

#define STORERF(R) do {                                                       \
    ASTF(R, 0, a0, a1) ASTF(R, 1, a2, a3) ASTF(R, 2, a4, a5) ASTF(R, 3, a6, a7)\
    BSTF(R, 0, 0, x) BSTF(R, 1, 0, y) BSTF(R, 2, 0, z) BSTF(R, 3, 0, w)       \
    BSTF(R, 4, 1, x) BSTF(R, 5, 1, y) BSTF(R, 6, 1, z) BSTF(R, 7, 1, w)       \
    BSTF(R, 8, 2, x) BSTF(R, 9, 2, y) BSTF(R,10, 2, z) BSTF(R,11, 2, w)       \
    BSTF(R,12, 3, x) BSTF(R,13, 3, y) BSTF(R,14, 3, z) BSTF(R,15, 3, w)       \
  } while (0)

  f32x16 acc00 = {}, acc01 = {}, acc10 = {}, acc11 = {};
  const char* Ard0 = Ab + (wr + lo5) * 128;
  const char* Ard1 = Ard0 + 32 * 128;
  const char* Brd0 = Bb + (wc + lo5) * 128;
  const char* Brd1 = Brd0 + 32 * 128;

#define MFMA_PHASE_F() do {                                                   \
    _Pragma("unroll")                                                         \
    for (int kk = 0; kk < 4; ++kk) {                                          \
      const int sb = ((((kk << 1) | hi1) ^ rs) << 4);                         \
      bf16x8 fa0 = *(const bf16x8*)(Ard0 + sb);                               \
      bf16x8 fa1 = *(const bf16x8*)(Ard1 + sb);                               \
      bf16x8 fb0 = *(const bf16x8*)(Brd0 + sb);                               \
      bf16x8 fb1 = *(const bf16x8*)(Brd1 + sb);                               \
      acc00 = __builtin_amdgcn_mfma_f32_32x32x16_bf16(fa0, fb0, acc00, 0,0,0);\
      acc01 = __builtin_amdgcn_mfma_f32_32x32x16_bf16(fa0, fb1, acc01, 0,0,0);\
      acc10 = __builtin_amdgcn_mfma_f32_32x32x16_bf16(fa1, fb0, acc10, 0,0,0);\
      acc11 = __builtin_amdgcn_mfma_f32_32x32x16_bf16(fa1, fb1, acc11, 0,0,0);\
    }                                                                         \
  } while (0)

  Regs r0, r1;
  LOADR(r0, 0);
#pragma unroll 1
  for (int s = 0; s < 8; s += 2) {
    STORERF(r0);
    __syncthreads();
    LOADR(r1, (s + 1) * BK);
    MFMA_PHASE_F();
    __syncthreads();
    STORERF(r1);
    __syncthreads();
    if (s + 2 < 8) LOADR(r0, (s + 2) * BK);
    MFMA_PHASE_F();
    __syncthreads();
  }

  const int gn0 = bn * 128 + wc + lo5;
  const int gn1 = gn0 + 32;
  const float bv0 = Bv[gn0];
  const float bv1 = Bv[gn1];
  EPI(acc00, 0, gn0, bv0);
  EPI(acc01, 0, gn1, bv1);
  EPI(acc10, 1, gn0, bv0);
  EPI(acc11, 1, gn1, bv1);
}

extern "C" void kernel_launch(void* const* d_in, const int* in_sizes, int n_in,
                              void* d_out, int out_size, void* d_ws, size_t ws_size,
                              hipStream_t stream) {
  (void)in_sizes; (void)n_in; (void)out_size;
  const float* X = (const float*)d_in[0];
  const float* W = (const float*)d_in[1];
  const float* b = (const float*)d_in[2];
  float* Y = (float*)d_out;
  if (ws_size >= WS_NEEDED) {
    uint8_t* Wt = (uint8_t*)d_ws;
    hipLaunchKernelGGL(cvtW_kernel, dim3(128),  dim3(256), 0, stream, W, Wt);
    hipLaunchKernelGGL(hotdd_fused, dim3(2048), dim3(256), 0, stream, X, Wt, b, Y);
  } else {
    hipLaunchKernelGGL(hotdd_fallback, dim3(2048), dim3(256), 0, stream, X, W, b, Y);
  }
}